// Round 1
// baseline (128.811 us; speedup 1.0000x reference)
//
#include <hip/hip_runtime.h>
#include <math.h>

// Kernel 1: scores[i] = dot(seq_feats[i,:], W_attn) + b
// One 64-lane wave per row, 4 waves (256 thr) per block. float4 loads.
__global__ void scores_kernel(const float* __restrict__ feats,
                              const float* __restrict__ Wv,
                              const float* __restrict__ bv,
                              float* __restrict__ scores,
                              int N, int H) {
    int wave = threadIdx.x >> 6;
    int lane = threadIdx.x & 63;
    int row  = blockIdx.x * 4 + wave;
    if (row >= N) return;
    const float4* f4 = reinterpret_cast<const float4*>(feats + (size_t)row * H);
    const float4* w4 = reinterpret_cast<const float4*>(Wv);
    int nvec = H >> 2;  // 256 for H=1024
    float acc = 0.f;
    for (int p = lane; p < nvec; p += 64) {
        float4 a = f4[p];
        float4 b = w4[p];
        acc += a.x * b.x + a.y * b.y + a.z * b.z + a.w * b.w;
    }
    // wave-64 reduction
    for (int off = 32; off > 0; off >>= 1)
        acc += __shfl_down(acc, off, 64);
    if (lane == 0) scores[row] = acc + bv[0];
}

// Kernel 2: start[d] = first index i with seg[i] >= d (seg is sorted).
// start has D+1 entries; start[D] = N.
__global__ void start_kernel(const int* __restrict__ seg,
                             int* __restrict__ start, int N, int D) {
    int d = blockIdx.x * blockDim.x + threadIdx.x;
    if (d > D) return;
    int lo = 0, hi = N;
    while (lo < hi) {
        int mid = (lo + hi) >> 1;
        if (seg[mid] < d) lo = mid + 1; else hi = mid;
    }
    start[d] = lo;
}

// Kernel 3: per-doc softmax stats; writes normalized weights w[i].
// One thread per doc (avg 8 rows/doc; scores is 256KB -> L2-resident).
__global__ void docstats_kernel(const float* __restrict__ scores,
                                const int* __restrict__ start,
                                float* __restrict__ w, int D) {
    int d = blockIdx.x * blockDim.x + threadIdx.x;
    if (d >= D) return;
    int s = start[d], e = start[d + 1];
    if (s >= e) return;  // empty doc: no rows, nothing to normalize
    float m = -INFINITY;
    for (int i = s; i < e; ++i) m = fmaxf(m, scores[i]);
    float denom = 0.f;
    for (int i = s; i < e; ++i) denom += __expf(scores[i] - m) * 0.f + expf(scores[i] - m);
    float inv = 1.0f / denom;
    for (int i = s; i < e; ++i) w[i] = expf(scores[i] - m) * inv;
}

// Kernel 4: doc_logits[d,c] = sum_i w[i]*seq_logits[i,c]  + mask offset.
// One block per doc; 250 active threads each own a float4 column group.
// Row stride = C*4 = 4000 bytes, 16B-aligned, so float4 loads are legal.
__global__ void docsum_kernel(const float* __restrict__ logits,
                              const float* __restrict__ w,
                              const int* __restrict__ start,
                              const float* __restrict__ mask,
                              float* __restrict__ out, int C) {
    int d = blockIdx.x;
    int nvec = C >> 2;  // 250 for C=1000
    int t = threadIdx.x;
    if (t >= nvec) return;
    int s = start[d], e = start[d + 1];
    const float4* l4 = reinterpret_cast<const float4*>(logits);
    float4 acc = make_float4(0.f, 0.f, 0.f, 0.f);
    for (int i = s; i < e; ++i) {
        float wi = w[i];  // scalar load, wave-broadcast from cache
        float4 v = l4[(size_t)i * nvec + t];
        acc.x += wi * v.x; acc.y += wi * v.y;
        acc.z += wi * v.z; acc.w += wi * v.w;
    }
    float4 mm = reinterpret_cast<const float4*>(mask)[t];
    float4 o;
    o.x = acc.x + (mm.x - 1.f) * 1e10f;
    o.y = acc.y + (mm.y - 1.f) * 1e10f;
    o.z = acc.z + (mm.z - 1.f) * 1e10f;
    o.w = acc.w + (mm.w - 1.f) * 1e10f;
    reinterpret_cast<float4*>(out)[(size_t)d * nvec + t] = o;
}

extern "C" void kernel_launch(void* const* d_in, const int* in_sizes, int n_in,
                              void* d_out, int out_size, void* d_ws, size_t ws_size,
                              hipStream_t stream) {
    const float* seq_feats  = (const float*)d_in[0];
    const float* seq_logits = (const float*)d_in[1];
    const float* W_attn     = (const float*)d_in[2];
    const float* b_attn     = (const float*)d_in[3];
    const float* mask       = (const float*)d_in[4];
    const int*   seg        = (const int*)d_in[5];

    int H = in_sizes[2];          // 1024 (W_attn is H x 1)
    int C = in_sizes[4];          // 1000 (doc_label_mask)
    int N = in_sizes[5];          // 65536 (segment_ids)
    int D = out_size / C;         // 8192

    float* scores = (float*)d_ws;          // N floats
    float* w      = scores + N;            // N floats
    int*   start  = (int*)(w + N);         // D+1 ints

    scores_kernel<<<(N + 3) / 4, 256, 0, stream>>>(seq_feats, W_attn, b_attn,
                                                   scores, N, H);
    start_kernel<<<(D + 1 + 255) / 256, 256, 0, stream>>>(seg, start, N, D);
    docstats_kernel<<<(D + 255) / 256, 256, 0, stream>>>(scores, start, w, D);
    docsum_kernel<<<D, 256, 0, stream>>>(seq_logits, w, start, mask,
                                         (float*)d_out, C);
}